// Round 1
// baseline (2409.229 us; speedup 1.0000x reference)
//
#include <hip/hip_runtime.h>
#include <hip/hip_fp16.h>

// DifferentiableRiskBudgeting: B=512 batches, P=256 assets.
// One block (256 threads) per batch. Sigma register/LDS-resident:
//   per-thread 16x16 tile; rows (r%16)<12 in VGPRs fp32 (192 regs),
//   rows (r%16)>=12 in LDS f16 (32 KB). launch_bounds(256,2) -> 2 blocks/CU.

#define PP 256
#define MAXW 0.1f
#define EPSF 1e-8f
#define NPGD 250
#define NBIS 30
#define NPOW 20

__device__ __forceinline__ float wsum(float x) {
#pragma unroll
    for (int m = 1; m < 64; m <<= 1) x += __shfl_xor(x, m, 64);
    return x;
}
__device__ __forceinline__ float wmin(float x) {
#pragma unroll
    for (int m = 1; m < 64; m <<= 1) x = fminf(x, __shfl_xor(x, m, 64));
    return x;
}
__device__ __forceinline__ float wmax(float x) {
#pragma unroll
    for (int m = 1; m < 64; m <<= 1) x = fmaxf(x, __shfl_xor(x, m, 64));
    return x;
}

__global__ __launch_bounds__(256, 2)
void drb_kernel(const float* __restrict__ sigma,
                const float* __restrict__ beta,
                const float* __restrict__ wprev,
                const float* __restrict__ pl1,
                const float* __restrict__ pl2,
                float* __restrict__ out)
{
    const int b    = blockIdx.x;
    const int tid  = threadIdx.x;
    const int lane = tid & 63;
    const int wv   = tid >> 6;
    const int ti   = tid >> 4;   // row group 0..15
    const int tj   = tid & 15;   // col group 0..15

    __shared__ __align__(16) __half sigH[64 * 256];  // 32 KB: rows with (r&15)>=12
    __shared__ __align__(16) float  wbuf[256];       // current vector (w or power v)
    __shared__ __align__(16) float  vbuf[256];       // scratch for reduce / bisection

    const float* Sb = sigma + (size_t)b * (PP * PP);

    // ---- load sigma tile: 12 fp32 rows -> registers (strided float4, L1 absorbs)
    float4 sreg[12][4];
#pragma unroll
    for (int r = 0; r < 12; ++r) {
        const float* rowp = Sb + (16 * ti + r) * PP + 16 * tj;
#pragma unroll
        for (int k = 0; k < 4; ++k) sreg[r][k] = *(const float4*)(rowp + 4 * k);
    }
    // ---- 4 f16 rows per row-group -> LDS, perfectly coalesced global reads
    for (int i = 0; i < 64; ++i) {
        int grow = (i >> 2) * 16 + 12 + (i & 3);
        sigH[i * 256 + tid] = __float2half(Sb[grow * 256 + tid]);
    }

    const float bt   = beta[b * PP + tid];
    const float wp   = wprev[b * PP + tid];
    const float lam1 = expf(pl1[0]);
    const float lam2 = expf(pl2[0]);

    // y = Sigma * wbuf ; returns y[tid] (thread t ends holding row t's sum)
    auto matvec = [&]() -> float {
        float y[16];
#pragma unroll
        for (int r = 0; r < 16; ++r) y[r] = 0.f;
#pragma unroll
        for (int k = 0; k < 4; ++k) {
            float4 w4 = *(const float4*)&wbuf[16 * tj + 4 * k];
#pragma unroll
            for (int r = 0; r < 12; ++r) {
                y[r] = fmaf(sreg[r][k].x, w4.x, y[r]);
                y[r] = fmaf(sreg[r][k].y, w4.y, y[r]);
                y[r] = fmaf(sreg[r][k].z, w4.z, y[r]);
                y[r] = fmaf(sreg[r][k].w, w4.w, y[r]);
            }
#pragma unroll
            for (int rr = 0; rr < 4; ++rr) {
                const __half2* ph =
                    (const __half2*)&sigH[(ti * 4 + rr) * 256 + 16 * tj + 4 * k];
                float2 f01 = __half22float2(ph[0]);
                float2 f23 = __half22float2(ph[1]);
                y[12 + rr] = fmaf(f01.x, w4.x, y[12 + rr]);
                y[12 + rr] = fmaf(f01.y, w4.y, y[12 + rr]);
                y[12 + rr] = fmaf(f23.x, w4.z, y[12 + rr]);
                y[12 + rr] = fmaf(f23.y, w4.w, y[12 + rr]);
            }
        }
        // transpose-reduce 16 partials across the 16 lanes of this row group;
        // after 4 steps lane tj holds full sum for row 16*ti + tj == tid.
#pragma unroll
        for (int m = 8, nv = 8; m >= 1; m >>= 1, nv >>= 1) {
            bool up = (tj & m) != 0;
#pragma unroll
            for (int kk = 0; kk < nv; ++kk) {
                float send = up ? y[kk] : y[kk + nv];
                float recv = __shfl_xor(send, m, 64);
                float keep = up ? y[kk + nv] : y[kk];
                y[kk] = keep + recv;
            }
        }
        return y[0];
    };

    // ---- power iteration: v0 = 1/sqrt(P)
    wbuf[tid] = 0.0625f;
    __syncthreads();
#pragma unroll 1
    for (int pi = 0; pi < NPOW; ++pi) {
        float u = matvec();
        vbuf[tid] = u;
        __syncthreads();
        float4 u4 = *(const float4*)&vbuf[4 * lane];
        float ss  = wsum(u4.x * u4.x + u4.y * u4.y + u4.z * u4.z + u4.w * u4.w);
        float inv = 1.f / (sqrtf(ss) + EPSF);
        if (wv == 0) {
            float4 n4 = make_float4(u4.x * inv, u4.y * inv, u4.z * inv, u4.w * inv);
            *(float4*)&wbuf[4 * lane] = n4;
        }
        __syncthreads();
    }

    // ---- lmax = v' S v ; step = 1/(2 lmax + 2 lam2 + 1e-6)
    {
        float y  = matvec();
        float vt = wbuf[tid];
        vbuf[tid] = vt * y;
        __syncthreads();
        float4 p4 = *(const float4*)&vbuf[4 * lane];
        float lmax = wsum(p4.x + p4.y + p4.z + p4.w);
        float stepf = 1.f / (2.f * lmax + 2.f * lam2 + 1e-6f);
        __syncthreads();           // vbuf reads done before PGD reuses it
        wbuf[tid] = 1.f / 256.f;   // w0
        __syncthreads();

        float w_t = 1.f / 256.f;

        // ---- PGD: 250 iterations, faithful 30-iter bisection projection
#pragma unroll 1
        for (int it = 0; it < NPGD; ++it) {
            float yv  = matvec();
            float g   = 2.f * yv - bt + lam1 + 2.f * lam2 * (w_t - wp);
            float v_t = w_t - stepf * g;
            vbuf[tid] = v_t;
            __syncthreads();
            // every wave redundantly runs the bisection (no broadcast barrier)
            float4 v4 = *(const float4*)&vbuf[4 * lane];
            float lo = wmin(fminf(fminf(v4.x, v4.y), fminf(v4.z, v4.w))) - MAXW;
            float hi = wmax(fmaxf(fmaxf(v4.x, v4.y), fmaxf(v4.z, v4.w)));
#pragma unroll 1
            for (int bi = 0; bi < NBIS; ++bi) {
                float tau = 0.5f * (lo + hi);
                float c0 = fminf(fmaxf(v4.x - tau, 0.f), MAXW);
                float c1 = fminf(fmaxf(v4.y - tau, 0.f), MAXW);
                float c2 = fminf(fmaxf(v4.z - tau, 0.f), MAXW);
                float c3 = fminf(fmaxf(v4.w - tau, 0.f), MAXW);
                float s  = wsum((c0 + c1) + (c2 + c3));
                bool big = s > 1.0f;
                lo = big ? tau : lo;
                hi = big ? hi : tau;
            }
            float tau = 0.5f * (lo + hi);
            w_t = fminf(fmaxf(v_t - tau, 0.f), MAXW);
            if (wv == 0) {
                float4 w4n = make_float4(
                    fminf(fmaxf(v4.x - tau, 0.f), MAXW),
                    fminf(fmaxf(v4.y - tau, 0.f), MAXW),
                    fminf(fmaxf(v4.z - tau, 0.f), MAXW),
                    fminf(fmaxf(v4.w - tau, 0.f), MAXW));
                *(float4*)&wbuf[4 * lane] = w4n;
            }
            __syncthreads();
        }

        // ---- renormalize and write out (w already in [0, MAXW])
        vbuf[tid] = w_t;
        __syncthreads();
        float4 wf = *(const float4*)&vbuf[4 * lane];
        float s = wsum(wf.x + wf.y + wf.z + wf.w);
        out[b * PP + tid] = w_t / (s + EPSF);
    }
}

extern "C" void kernel_launch(void* const* d_in, const int* in_sizes, int n_in,
                              void* d_out, int out_size, void* d_ws, size_t ws_size,
                              hipStream_t stream) {
    const float* sigma = (const float*)d_in[0];
    const float* beta  = (const float*)d_in[1];
    const float* wprevp= (const float*)d_in[2];
    const float* pl1   = (const float*)d_in[3];
    const float* pl2   = (const float*)d_in[4];
    float* outp = (float*)d_out;
    drb_kernel<<<dim3(512), dim3(256), 0, stream>>>(sigma, beta, wprevp, pl1, pl2, outp);
}

// Round 2
// 1360.289 us; speedup vs baseline: 1.7711x; 1.7711x over previous
//
#include <hip/hip_runtime.h>
#include <math.h>

// DifferentiableRiskBudgeting: B=512, P=256. One block (256 thr) per batch.
// Tiling: thread (ti=tid>>2, tj=tid&3) owns rows 4ti..4ti+3, cols 64tj..64tj+63.
//   Rows 4ti+0..2: fp32 in VGPRs (192 regs). Row 4ti+3: fp32 in LDS,
//   column-major with per-tj stagger (2-way banks = free).
// All cross-lane reductions via DPP (VALU pipe), no ds_swizzle chains.
// One __syncthreads per PGD iteration (double-buffered v, clip folded into
// the matvec w-load with uniform tau).

#define PP    256
#define MAXW  0.1f
#define EPSF  1e-8f
#define NPGD  250
#define NBIS  30
#define NPOW  20
#define FLTMX 3.402823466e+38f

// sigF layout: [tj][col' (0..63)][ti (0..63)], block stride 4104 (pad 8) for banks
#define SIG3_STRIDE 4104
// v buffers: 4 copies, copy c at offset c*264 (stagger 8); element e at c*264+e
#define VCOPY 264

template<int CTRL>
__device__ __forceinline__ float dpp_zero(float x) {
    return __int_as_float(__builtin_amdgcn_update_dpp(
        0, __float_as_int(x), CTRL, 0xF, 0xF, true));
}
template<int CTRL>
__device__ __forceinline__ float dpp_keep(float x) {
    int xi = __float_as_int(x);
    return __int_as_float(__builtin_amdgcn_update_dpp(xi, xi, CTRL, 0xF, 0xF, false));
}
__device__ __forceinline__ float rdlane63(float x) {
    return __int_as_float(__builtin_amdgcn_readlane(__float_as_int(x), 63));
}
// prefix-style reduce: lane 63 ends with full-wave result
__device__ __forceinline__ float wave_sum63(float s) {
    s += dpp_zero<0x111>(s);   // row_shr:1
    s += dpp_zero<0x112>(s);   // row_shr:2
    s += dpp_zero<0x114>(s);   // row_shr:4
    s += dpp_zero<0x118>(s);   // row_shr:8
    s += dpp_zero<0x142>(s);   // row_bcast15
    s += dpp_zero<0x143>(s);   // row_bcast31
    return s;
}
__device__ __forceinline__ float wave_min63(float m) {
    m = fminf(m, dpp_keep<0x111>(m));
    m = fminf(m, dpp_keep<0x112>(m));
    m = fminf(m, dpp_keep<0x114>(m));
    m = fminf(m, dpp_keep<0x118>(m));
    m = fminf(m, dpp_keep<0x142>(m));
    m = fminf(m, dpp_keep<0x143>(m));
    return m;
}
__device__ __forceinline__ float wave_max63(float m) {
    m = fmaxf(m, dpp_keep<0x111>(m));
    m = fmaxf(m, dpp_keep<0x112>(m));
    m = fmaxf(m, dpp_keep<0x114>(m));
    m = fmaxf(m, dpp_keep<0x118>(m));
    m = fmaxf(m, dpp_keep<0x142>(m));
    m = fmaxf(m, dpp_keep<0x143>(m));
    return m;
}

__global__ __launch_bounds__(256, 2)
void drb_kernel(const float* __restrict__ sigma,
                const float* __restrict__ beta,
                const float* __restrict__ wprev,
                const float* __restrict__ pl1,
                const float* __restrict__ pl2,
                float* __restrict__ out)
{
    const int b    = blockIdx.x;
    const int tid  = threadIdx.x;
    const int lane = tid & 63;
    const int ti   = tid >> 2;   // 0..63 (row group of 4)
    const int tj   = tid & 3;    // 0..3  (col group of 64)

    __shared__ __align__(16) float sigF[4 * SIG3_STRIDE];  // ~64 KB, row-3 data
    __shared__ __align__(16) float bufA[3 * VCOPY + 256];  // 4 staggered v-copies
    __shared__ __align__(16) float bufB[3 * VCOPY + 256];

    const float* Sb = sigma + (size_t)b * (PP * PP);

    // ---- stage sigma: rows 4ti..4ti+2 -> VGPRs, row 4ti+3 -> LDS column-major
    float4 sreg[3][16];
#pragma unroll
    for (int r = 0; r < 3; ++r) {
        const float* rowp = Sb + (4 * ti + r) * PP + 64 * tj;
#pragma unroll
        for (int k = 0; k < 16; ++k) sreg[r][k] = *(const float4*)(rowp + 4 * k);
    }
    {
        const float* rowp = Sb + (4 * ti + 3) * PP + 64 * tj;
        float* s3 = sigF + SIG3_STRIDE * tj + ti;
#pragma unroll
        for (int k = 0; k < 16; ++k) {
            float4 t = *(const float4*)(rowp + 4 * k);
            s3[(4 * k + 0) * 64] = t.x;
            s3[(4 * k + 1) * 64] = t.y;
            s3[(4 * k + 2) * 64] = t.z;
            s3[(4 * k + 3) * 64] = t.w;
        }
    }

    const float bt   = beta[b * PP + tid];
    const float wp   = wprev[b * PP + tid];
    const float lam1 = expf(pl1[0]);
    const float lam2 = expf(pl2[0]);

    // y = Sigma * T(v) where T(v) = med3(v*a + bb, lo_t, hi_t); returns y[row tid]
    auto matvec = [&](const float* __restrict__ vb, float a, float bb,
                      float lo_t, float hi_t) -> float {
        float y0 = 0.f, y1 = 0.f, y2 = 0.f, y3 = 0.f;
        const float* vp = vb + 328 * tj;            // copy tj + element offset 64*tj
        const float* p3 = sigF + SIG3_STRIDE * tj + ti;
#pragma unroll
        for (int k = 0; k < 16; ++k) {
            float4 w4 = *(const float4*)(vp + 4 * k);
            w4.x = fminf(fmaxf(fmaf(w4.x, a, bb), lo_t), hi_t);
            w4.y = fminf(fmaxf(fmaf(w4.y, a, bb), lo_t), hi_t);
            w4.z = fminf(fmaxf(fmaf(w4.z, a, bb), lo_t), hi_t);
            w4.w = fminf(fmaxf(fmaf(w4.w, a, bb), lo_t), hi_t);
            const float4 s0 = sreg[0][k], s1 = sreg[1][k], s2 = sreg[2][k];
            y0 = fmaf(s0.x, w4.x, y0); y0 = fmaf(s0.y, w4.y, y0);
            y0 = fmaf(s0.z, w4.z, y0); y0 = fmaf(s0.w, w4.w, y0);
            y1 = fmaf(s1.x, w4.x, y1); y1 = fmaf(s1.y, w4.y, y1);
            y1 = fmaf(s1.z, w4.z, y1); y1 = fmaf(s1.w, w4.w, y1);
            y2 = fmaf(s2.x, w4.x, y2); y2 = fmaf(s2.y, w4.y, y2);
            y2 = fmaf(s2.z, w4.z, y2); y2 = fmaf(s2.w, w4.w, y2);
            const float* q = p3 + 256 * k;
            y3 = fmaf(q[0],   w4.x, y3);
            y3 = fmaf(q[64],  w4.y, y3);
            y3 = fmaf(q[128], w4.z, y3);
            y3 = fmaf(q[192], w4.w, y3);
        }
        // quad reduction via DPP quad_perm (xor2 then xor1): all quad lanes get
        // full row sums; thread keeps row (tj)
        y0 += dpp_zero<0x4E>(y0); y1 += dpp_zero<0x4E>(y1);
        y2 += dpp_zero<0x4E>(y2); y3 += dpp_zero<0x4E>(y3);
        y0 += dpp_zero<0xB1>(y0); y1 += dpp_zero<0xB1>(y1);
        y2 += dpp_zero<0xB1>(y2); y3 += dpp_zero<0xB1>(y3);
        float r01 = (tj & 1) ? y1 : y0;
        float r23 = (tj & 1) ? y3 : y2;
        return (tj & 2) ? r23 : r01;
    };

    // ---- init v0 = 1/16 into bufA (all 4 copies)
#pragma unroll
    for (int c = 0; c < 4; ++c) bufA[c * VCOPY + tid] = 0.0625f;
    __syncthreads();

    float* RD = bufA;
    float* WR = bufB;
    float a_cur = 1.0f;   // scale applied to RD on read (normalization folded)
    float u_own = 0.0f;

    // ---- power iteration (20)
#pragma unroll 1
    for (int pi = 0; pi < NPOW; ++pi) {
        float y = matvec(RD, a_cur, 0.f, -FLTMX, FLTMX);
        u_own = y;
#pragma unroll
        for (int c = 0; c < 4; ++c) WR[c * VCOPY + tid] = y;
        __syncthreads();
        float4 u4 = *(const float4*)(WR + 4 * lane);
        float ss = fmaf(u4.x, u4.x, fmaf(u4.y, u4.y, fmaf(u4.z, u4.z, u4.w * u4.w)));
        float tot = rdlane63(wave_sum63(ss));
        a_cur = 1.f / (sqrtf(tot) + EPSF);
        float* t = RD; RD = WR; WR = t;
    }

    // ---- lmax = v' S v ; step
    float stepf;
    {
        float y = matvec(RD, a_cur, 0.f, -FLTMX, FLTMX);
        float p = u_own * a_cur * y;
        WR[tid] = p;                        // copy 0 only
        __syncthreads();
        float4 p4 = *(const float4*)(WR + 4 * lane);
        float lmax = rdlane63(wave_sum63((p4.x + p4.y) + (p4.z + p4.w)));
        stepf = 1.f / (2.f * lmax + 2.f * lam2 + 1e-6f);
        __syncthreads();                    // WR reads done before PGD overwrites
    }

    // ---- PGD (250 iters, faithful 30-round bisection, DPP reductions)
    float w_own = 1.f / 256.f;
    float ta = 0.f, tb = 1.f / 256.f, tlo = -FLTMX, thi = FLTMX;  // it0: w == 1/256
#pragma unroll 1
    for (int it = 0; it < NPGD; ++it) {
        float y = matvec(RD, ta, tb, tlo, thi);
        float g = 2.f * y - bt + lam1 + 2.f * lam2 * (w_own - wp);
        float v_own = w_own - stepf * g;
#pragma unroll
        for (int c = 0; c < 4; ++c) WR[c * VCOPY + tid] = v_own;
        __syncthreads();
        float4 v4 = *(const float4*)(WR + 4 * lane);
        float mn = rdlane63(wave_min63(fminf(fminf(v4.x, v4.y), fminf(v4.z, v4.w))));
        float mx = rdlane63(wave_max63(fmaxf(fmaxf(v4.x, v4.y), fmaxf(v4.z, v4.w))));
        float lo = mn - MAXW, hi = mx;
#pragma unroll 1
        for (int bi = 0; bi < NBIS; ++bi) {
            float tau = 0.5f * (lo + hi);
            float c0 = fminf(fmaxf(v4.x - tau, 0.f), MAXW);
            float c1 = fminf(fmaxf(v4.y - tau, 0.f), MAXW);
            float c2 = fminf(fmaxf(v4.z - tau, 0.f), MAXW);
            float c3 = fminf(fmaxf(v4.w - tau, 0.f), MAXW);
            float s = rdlane63(wave_sum63((c0 + c1) + (c2 + c3)));
            bool big = s > 1.0f;
            lo = big ? tau : lo;
            hi = big ? hi : tau;
        }
        float tau = 0.5f * (lo + hi);
        w_own = fminf(fmaxf(v_own - tau, 0.f), MAXW);
        ta = 1.f; tb = -tau; tlo = 0.f; thi = MAXW;
        float* t = RD; RD = WR; WR = t;
    }

    // ---- renormalize + store
    WR[tid] = w_own;
    __syncthreads();
    float4 w4 = *(const float4*)(WR + 4 * lane);
    float S = rdlane63(wave_sum63((w4.x + w4.y) + (w4.z + w4.w)));
    out[b * PP + tid] = w_own / (S + EPSF);
}

extern "C" void kernel_launch(void* const* d_in, const int* in_sizes, int n_in,
                              void* d_out, int out_size, void* d_ws, size_t ws_size,
                              hipStream_t stream) {
    const float* sigma  = (const float*)d_in[0];
    const float* beta   = (const float*)d_in[1];
    const float* wprevp = (const float*)d_in[2];
    const float* pl1    = (const float*)d_in[3];
    const float* pl2    = (const float*)d_in[4];
    float* outp = (float*)d_out;
    drb_kernel<<<dim3(512), dim3(256), 0, stream>>>(sigma, beta, wprevp, pl1, pl2, outp);
}

// Round 3
// 1111.883 us; speedup vs baseline: 2.1668x; 1.2234x over previous
//
#include <hip/hip_runtime.h>
#include <math.h>

// DifferentiableRiskBudgeting: B=512, P=256. One block (256 thr) per batch.
// Thread (ti=tid>>2, tj=tid&3) owns rows 4ti..4ti+3 x cols 64tj..64tj+63.
//   Rows +0..2: fp32 VGPRs as float2 (even/odd col pairs) -> v_pk_fma_f32.
//   Row  +3: fp32 LDS, row-major, pad to 260 floats (balanced banks, b128).
// w is stored PROJECTED (4 staggered copies, one written per wave) so the
// matvec inner loop is pure FMA. Projection via 12-round Illinois
// regula-falsi with analytically known bracket endpoint values.
// All reductions on the DPP/VALU path; 2 barriers per PGD iteration.

#define PP    256
#define MAXW  0.1f
#define EPSF  1e-8f
#define NPGD  250
#define NPOW  20
#define NILL  12

#define R3S   260   // padded floats per LDS sigma row
#define VCOPY 264   // stagger between w copies

typedef float v2 __attribute__((ext_vector_type(2)));

template<int CTRL>
__device__ __forceinline__ float dpp_zero(float x) {
    return __int_as_float(__builtin_amdgcn_update_dpp(
        0, __float_as_int(x), CTRL, 0xF, 0xF, true));
}
template<int CTRL>
__device__ __forceinline__ float dpp_keep(float x) {
    int xi = __float_as_int(x);
    return __int_as_float(__builtin_amdgcn_update_dpp(xi, xi, CTRL, 0xF, 0xF, false));
}
__device__ __forceinline__ float rdlane63(float x) {
    return __int_as_float(__builtin_amdgcn_readlane(__float_as_int(x), 63));
}
__device__ __forceinline__ float wave_sum63(float s) {
    s += dpp_zero<0x111>(s);
    s += dpp_zero<0x112>(s);
    s += dpp_zero<0x114>(s);
    s += dpp_zero<0x118>(s);
    s += dpp_zero<0x142>(s);
    s += dpp_zero<0x143>(s);
    return s;
}
__device__ __forceinline__ float wave_min63(float m) {
    m = fminf(m, dpp_keep<0x111>(m));
    m = fminf(m, dpp_keep<0x112>(m));
    m = fminf(m, dpp_keep<0x114>(m));
    m = fminf(m, dpp_keep<0x118>(m));
    m = fminf(m, dpp_keep<0x142>(m));
    m = fminf(m, dpp_keep<0x143>(m));
    return m;
}
__device__ __forceinline__ float wave_max63(float m) {
    m = fmaxf(m, dpp_keep<0x111>(m));
    m = fmaxf(m, dpp_keep<0x112>(m));
    m = fmaxf(m, dpp_keep<0x114>(m));
    m = fmaxf(m, dpp_keep<0x118>(m));
    m = fmaxf(m, dpp_keep<0x142>(m));
    m = fmaxf(m, dpp_keep<0x143>(m));
    return m;
}

__global__ __launch_bounds__(256, 2)
void drb_kernel(const float* __restrict__ sigma,
                const float* __restrict__ beta,
                const float* __restrict__ wprev,
                const float* __restrict__ pl1,
                const float* __restrict__ pl2,
                float* __restrict__ out)
{
    const int b    = blockIdx.x;
    const int tid  = threadIdx.x;
    const int lane = tid & 63;
    const int wv   = tid >> 6;
    const int ti   = tid >> 2;   // 0..63
    const int tj   = tid & 3;    // 0..3

    __shared__ __align__(16) float sigR3[64 * R3S];   // 66560 B
    __shared__ __align__(16) float wcop[4 * VCOPY];   // 4 staggered w copies
    __shared__ __align__(16) float stage[264];        // cross-wave transpose buf

    const float* Sb = sigma + (size_t)b * (PP * PP);

    // ---- stage sigma: rows +0..2 -> float2 VGPR pairs; row +3 -> LDS row-major
    v2 s0[32], s1[32], s2[32];
    {
        const float* r0 = Sb + (4 * ti + 0) * PP + 64 * tj;
        const float* r1 = Sb + (4 * ti + 1) * PP + 64 * tj;
        const float* r2 = Sb + (4 * ti + 2) * PP + 64 * tj;
#pragma unroll
        for (int k = 0; k < 16; ++k) {
            float4 t0 = *(const float4*)(r0 + 4 * k);
            float4 t1 = *(const float4*)(r1 + 4 * k);
            float4 t2 = *(const float4*)(r2 + 4 * k);
            s0[2*k].x = t0.x; s0[2*k].y = t0.y; s0[2*k+1].x = t0.z; s0[2*k+1].y = t0.w;
            s1[2*k].x = t1.x; s1[2*k].y = t1.y; s1[2*k+1].x = t1.z; s1[2*k+1].y = t1.w;
            s2[2*k].x = t2.x; s2[2*k].y = t2.y; s2[2*k+1].x = t2.z; s2[2*k+1].y = t2.w;
        }
        const float* r3 = Sb + (4 * ti + 3) * PP + 64 * tj;
        float* d3 = sigR3 + ti * R3S + 64 * tj;
#pragma unroll
        for (int k = 0; k < 16; ++k)
            *(float4*)(d3 + 4 * k) = *(const float4*)(r3 + 4 * k);
    }

    const float bt   = beta[b * PP + tid];
    const float wp   = wprev[b * PP + tid];
    const float lam1 = expf(pl1[0]);
    const float lam2 = expf(pl2[0]);

    // y = Sigma * w (w read from wcop copy tj); returns y[row tid]
    auto matvec = [&]() -> float {
        v2 y0 = {0.f, 0.f}, y1 = {0.f, 0.f}, y2 = {0.f, 0.f}, y3 = {0.f, 0.f};
        const float* vp = wcop + 328 * tj;           // tj*VCOPY + 64*tj
        const float* p3 = sigR3 + ti * R3S + 64 * tj;
#pragma unroll
        for (int k = 0; k < 16; ++k) {
            float4 wq = *(const float4*)(vp + 4 * k);
            v2 w01; w01.x = wq.x; w01.y = wq.y;
            v2 w23; w23.x = wq.z; w23.y = wq.w;
            y0 = __builtin_elementwise_fma(s0[2*k],   w01, y0);
            y0 = __builtin_elementwise_fma(s0[2*k+1], w23, y0);
            y1 = __builtin_elementwise_fma(s1[2*k],   w01, y1);
            y1 = __builtin_elementwise_fma(s1[2*k+1], w23, y1);
            y2 = __builtin_elementwise_fma(s2[2*k],   w01, y2);
            y2 = __builtin_elementwise_fma(s2[2*k+1], w23, y2);
            float4 q = *(const float4*)(p3 + 4 * k);
            v2 q01; q01.x = q.x; q01.y = q.y;
            v2 q23; q23.x = q.z; q23.y = q.w;
            y3 = __builtin_elementwise_fma(q01, w01, y3);
            y3 = __builtin_elementwise_fma(q23, w23, y3);
        }
        float r0 = y0.x + y0.y, r1 = y1.x + y1.y;
        float r2 = y2.x + y2.y, r3 = y3.x + y3.y;
        // quad all-reduce: xor2 then xor1 via quad_perm
        r0 += dpp_zero<0x4E>(r0); r1 += dpp_zero<0x4E>(r1);
        r2 += dpp_zero<0x4E>(r2); r3 += dpp_zero<0x4E>(r3);
        r0 += dpp_zero<0xB1>(r0); r1 += dpp_zero<0xB1>(r1);
        r2 += dpp_zero<0xB1>(r2); r3 += dpp_zero<0xB1>(r3);
        float a01 = (tj & 1) ? r1 : r0;
        float a23 = (tj & 1) ? r3 : r2;
        return (tj & 2) ? a23 : a01;
    };

    // ---- power iteration: v0 = 1/16 everywhere
#pragma unroll
    for (int c = 0; c < 4; ++c) wcop[c * VCOPY + tid] = 0.0625f;
    __syncthreads();

    float y_last = 0.f, a_last = 1.f;
#pragma unroll 1
    for (int pi = 0; pi < NPOW; ++pi) {
        float y = matvec();
        stage[tid] = y;
        __syncthreads();
        float4 u4 = *(const float4*)(stage + 4 * lane);
        float ss = fmaf(u4.x, u4.x, fmaf(u4.y, u4.y, fmaf(u4.z, u4.z, u4.w * u4.w)));
        float a  = 1.f / (sqrtf(rdlane63(wave_sum63(ss))) + EPSF);
        float4 n4 = make_float4(a * u4.x, a * u4.y, a * u4.z, a * u4.w);
        *(float4*)(wcop + wv * VCOPY + 4 * lane) = n4;   // wave wv -> copy wv
        y_last = y; a_last = a;
        __syncthreads();
    }

    // ---- lmax = v' S v ; step
    float stepf;
    {
        float ysv = matvec();                 // S v (v normalized in wcop)
        float p   = (a_last * y_last) * ysv;  // v_own * (Sv)_own
        stage[tid] = p;
        __syncthreads();
        float4 p4 = *(const float4*)(stage + 4 * lane);
        float lmax = rdlane63(wave_sum63((p4.x + p4.y) + (p4.z + p4.w)));
        stepf = 1.f / (2.f * lmax + 2.f * lam2 + 1e-6f);
        __syncthreads();
    }

    // ---- PGD
    float w_own = 1.f / 256.f;
#pragma unroll
    for (int c = 0; c < 4; ++c) wcop[c * VCOPY + tid] = 1.f / 256.f;
    const float Ac = 1.f - 2.f * lam2 * stepf;
    const float Bc = -2.f * stepf;
    const float Cc = stepf * (bt - lam1 + 2.f * lam2 * wp);
    __syncthreads();

#pragma unroll 1
    for (int it = 0; it < NPGD; ++it) {
        float y = matvec();
        float v_own = fmaf(w_own, Ac, fmaf(y, Bc, Cc));
        stage[tid] = v_own;
        __syncthreads();

        float4 v4 = *(const float4*)(stage + 4 * lane);
        float mn = rdlane63(wave_min63(fminf(fminf(v4.x, v4.y), fminf(v4.z, v4.w))));
        float mx = rdlane63(wave_max63(fmaxf(fmaxf(v4.x, v4.y), fmaxf(v4.z, v4.w))));

        // Illinois regula-falsi on f(tau) = s(tau) - 1, known endpoints:
        //   s(mn - MAXW) = 256*MAXW, s(mx) = 0
        float lo = mn - MAXW, flo = 256.f * MAXW - 1.f;
        float hi = mx,        fhi = -1.f;
        int side = 0;   // +1 last update was lo, -1 last was hi
        float tau = 0.f;
#pragma unroll 1
        for (int r = 0; r < NILL; ++r) {
            tau = (lo * fhi - hi * flo) / (fhi - flo);
            float c0 = __builtin_amdgcn_fmed3f(v4.x - tau, 0.f, MAXW);
            float c1 = __builtin_amdgcn_fmed3f(v4.y - tau, 0.f, MAXW);
            float c2 = __builtin_amdgcn_fmed3f(v4.z - tau, 0.f, MAXW);
            float c3 = __builtin_amdgcn_fmed3f(v4.w - tau, 0.f, MAXW);
            float f = rdlane63(wave_sum63((c0 + c1) + (c2 + c3))) - 1.f;
            bool pos = f > 0.f;
            float nflo = pos ? f   : ((side == -1) ? 0.5f * flo : flo);
            float nfhi = pos ? ((side == +1) ? 0.5f * fhi : fhi) : f;
            lo  = pos ? tau : lo;
            hi  = pos ? hi  : tau;
            flo = nflo; fhi = nfhi;
            side = pos ? +1 : -1;
        }
        tau = (lo * fhi - hi * flo) / (fhi - flo);   // final secant estimate

        float4 w4 = make_float4(
            __builtin_amdgcn_fmed3f(v4.x - tau, 0.f, MAXW),
            __builtin_amdgcn_fmed3f(v4.y - tau, 0.f, MAXW),
            __builtin_amdgcn_fmed3f(v4.z - tau, 0.f, MAXW),
            __builtin_amdgcn_fmed3f(v4.w - tau, 0.f, MAXW));
        *(float4*)(wcop + wv * VCOPY + 4 * lane) = w4;   // wave wv -> copy wv
        w_own = __builtin_amdgcn_fmed3f(v_own - tau, 0.f, MAXW);
        __syncthreads();
    }

    // ---- renormalize + store
    stage[tid] = w_own;
    __syncthreads();
    float4 w4 = *(const float4*)(stage + 4 * lane);
    float S = rdlane63(wave_sum63((w4.x + w4.y) + (w4.z + w4.w)));
    out[b * PP + tid] = w_own / (S + EPSF);
}

extern "C" void kernel_launch(void* const* d_in, const int* in_sizes, int n_in,
                              void* d_out, int out_size, void* d_ws, size_t ws_size,
                              hipStream_t stream) {
    const float* sigma  = (const float*)d_in[0];
    const float* beta   = (const float*)d_in[1];
    const float* wprevp = (const float*)d_in[2];
    const float* pl1    = (const float*)d_in[3];
    const float* pl2    = (const float*)d_in[4];
    float* outp = (float*)d_out;
    drb_kernel<<<dim3(512), dim3(256), 0, stream>>>(sigma, beta, wprevp, pl1, pl2, outp);
}

// Round 5
// 855.995 us; speedup vs baseline: 2.8145x; 1.2989x over previous
//
#include <hip/hip_runtime.h>
#include <math.h>

// DifferentiableRiskBudgeting: B=512, P=256. One block (256 thr) per batch.
// Thread (ti=tid>>2, tj=tid&3) owns rows 4ti..4ti+3 x cols 64tj..64tj+63.
//   Rows +0..2: fp32 VGPRs as <2 x float> pairs -> v_pk_fma_f32.
//   Row  +3: fp32 LDS slab, stride 272 + tj-stride 68 => every 8 consecutive
//   lanes' b128 segments tile all 32 banks (conflict-free, 8-lane phasing).
// One barrier per PGD iteration: after the stage gather every wave holds the
// full v, so each wave writes the complete projected w into its OWN wcop
// copy (wave-local, lgkmcnt-ordered). Stage is double-buffered.
// w-copy layout: element block tj (64 elems) starts at 72*tj (8-float stagger)
//   -> write via wst = 4*lane + 8*(lane>>4); read base WRDS*tj, WRDS=72.
//   (R4 bug: read used the sigma-slab stride 68 here.)
// Projection: 10-round Illinois regula-falsi, v_rcp_f32 for the secant.

#define PP    256
#define MAXW  0.1f
#define EPSF  1e-8f
#define NPGD  250
#define NPOW  20
#define NILL  10

#define R3S   272   // sigma row-3 slab stride (floats); 272 % 32 == 16
#define TJS   68    // tj stride inside slab row;        68 % 32 == 4
#define WRDS  72    // w-copy block stride (64 data + 8 stagger)
#define VCOPY 280   // per-wave w copy stride (3*72 + 64 = 280)

typedef float v2 __attribute__((ext_vector_type(2)));
typedef float v4t __attribute__((ext_vector_type(4)));

template<int CTRL>
__device__ __forceinline__ float dpp_zero(float x) {
    return __int_as_float(__builtin_amdgcn_update_dpp(
        0, __float_as_int(x), CTRL, 0xF, 0xF, true));
}
template<int CTRL>
__device__ __forceinline__ float dpp_keep(float x) {
    int xi = __float_as_int(x);
    return __int_as_float(__builtin_amdgcn_update_dpp(xi, xi, CTRL, 0xF, 0xF, false));
}
__device__ __forceinline__ float rdlane63(float x) {
    return __int_as_float(__builtin_amdgcn_readlane(__float_as_int(x), 63));
}
__device__ __forceinline__ float wave_sum63(float s) {
    s += dpp_zero<0x111>(s);
    s += dpp_zero<0x112>(s);
    s += dpp_zero<0x114>(s);
    s += dpp_zero<0x118>(s);
    s += dpp_zero<0x142>(s);
    s += dpp_zero<0x143>(s);
    return s;
}
__device__ __forceinline__ float wave_min63(float m) {
    m = fminf(m, dpp_keep<0x111>(m));
    m = fminf(m, dpp_keep<0x112>(m));
    m = fminf(m, dpp_keep<0x114>(m));
    m = fminf(m, dpp_keep<0x118>(m));
    m = fminf(m, dpp_keep<0x142>(m));
    m = fminf(m, dpp_keep<0x143>(m));
    return m;
}
__device__ __forceinline__ float wave_max63(float m) {
    m = fmaxf(m, dpp_keep<0x111>(m));
    m = fmaxf(m, dpp_keep<0x112>(m));
    m = fmaxf(m, dpp_keep<0x114>(m));
    m = fmaxf(m, dpp_keep<0x118>(m));
    m = fmaxf(m, dpp_keep<0x142>(m));
    m = fmaxf(m, dpp_keep<0x143>(m));
    return m;
}

__global__ __launch_bounds__(256, 2)
void drb_kernel(const float* __restrict__ sigma,
                const float* __restrict__ beta,
                const float* __restrict__ wprev,
                const float* __restrict__ pl1,
                const float* __restrict__ pl2,
                float* __restrict__ out)
{
    const int b    = blockIdx.x;
    const int tid  = threadIdx.x;
    const int lane = tid & 63;
    const int wv   = tid >> 6;
    const int ti   = tid >> 2;   // 0..63
    const int tj   = tid & 3;    // 0..3

    __shared__ __align__(16) float sigR3[64 * R3S];   // 69632 B
    __shared__ __align__(16) float wcop[4 * VCOPY];   //  4480 B
    __shared__ __align__(16) float stage[2][256];     //  2048 B

    const float* Sb = sigma + (size_t)b * (PP * PP);

    // ---- stage sigma: rows +0..2 -> v2 VGPR pairs; row +3 -> LDS slab
    v2 s0[32], s1[32], s2[32];
    {
        const float* r0 = Sb + (4 * ti + 0) * PP + 64 * tj;
        const float* r1 = Sb + (4 * ti + 1) * PP + 64 * tj;
        const float* r2 = Sb + (4 * ti + 2) * PP + 64 * tj;
#pragma unroll
        for (int k = 0; k < 16; ++k) {
            v4t t0 = *(const v4t*)(r0 + 4 * k);
            v4t t1 = *(const v4t*)(r1 + 4 * k);
            v4t t2 = *(const v4t*)(r2 + 4 * k);
            s0[2*k]   = __builtin_shufflevector(t0, t0, 0, 1);
            s0[2*k+1] = __builtin_shufflevector(t0, t0, 2, 3);
            s1[2*k]   = __builtin_shufflevector(t1, t1, 0, 1);
            s1[2*k+1] = __builtin_shufflevector(t1, t1, 2, 3);
            s2[2*k]   = __builtin_shufflevector(t2, t2, 0, 1);
            s2[2*k+1] = __builtin_shufflevector(t2, t2, 2, 3);
        }
        const float* r3 = Sb + (4 * ti + 3) * PP + 64 * tj;
        float* d3 = sigR3 + ti * R3S + TJS * tj;
#pragma unroll
        for (int k = 0; k < 16; ++k)
            *(v4t*)(d3 + 4 * k) = *(const v4t*)(r3 + 4 * k);
        // row-3 slab is written and read by the SAME thread -> no barrier.
    }

    const float bt   = beta[b * PP + tid];
    const float wp   = wprev[b * PP + tid];
    const float lam1 = expf(pl1[0]);
    const float lam2 = expf(pl2[0]);

    float* wme = wcop + wv * VCOPY;                // my wave's full-vector copy
    const int wst = 4 * lane + 8 * (lane >> 4);    // staggered write slot
    const float* wrd = wme + WRDS * tj;            // matvec read base (72*tj)

    // y = Sigma * w (w from my wave's copy); returns y[row tid]
    auto matvec = [&]() -> float {
        v2 y0 = {0.f, 0.f}, y1 = {0.f, 0.f}, y2 = {0.f, 0.f}, y3 = {0.f, 0.f};
        const float* p3 = sigR3 + ti * R3S + TJS * tj;
#pragma unroll
        for (int k = 0; k < 16; ++k) {
            v4t wq = *(const v4t*)(wrd + 4 * k);
            v2 w01 = __builtin_shufflevector(wq, wq, 0, 1);
            v2 w23 = __builtin_shufflevector(wq, wq, 2, 3);
            y0 = __builtin_elementwise_fma(s0[2*k],   w01, y0);
            y0 = __builtin_elementwise_fma(s0[2*k+1], w23, y0);
            y1 = __builtin_elementwise_fma(s1[2*k],   w01, y1);
            y1 = __builtin_elementwise_fma(s1[2*k+1], w23, y1);
            y2 = __builtin_elementwise_fma(s2[2*k],   w01, y2);
            y2 = __builtin_elementwise_fma(s2[2*k+1], w23, y2);
            v4t q = *(const v4t*)(p3 + 4 * k);
            v2 q01 = __builtin_shufflevector(q, q, 0, 1);
            v2 q23 = __builtin_shufflevector(q, q, 2, 3);
            y3 = __builtin_elementwise_fma(q01, w01, y3);
            y3 = __builtin_elementwise_fma(q23, w23, y3);
        }
        float r0 = y0.x + y0.y, r1 = y1.x + y1.y;
        float r2 = y2.x + y2.y, r3 = y3.x + y3.y;
        r0 += dpp_zero<0x4E>(r0); r1 += dpp_zero<0x4E>(r1);
        r2 += dpp_zero<0x4E>(r2); r3 += dpp_zero<0x4E>(r3);
        r0 += dpp_zero<0xB1>(r0); r1 += dpp_zero<0xB1>(r1);
        r2 += dpp_zero<0xB1>(r2); r3 += dpp_zero<0xB1>(r3);
        float a01 = (tj & 1) ? r1 : r0;
        float a23 = (tj & 1) ? r3 : r2;
        return (tj & 2) ? a23 : a01;
    };

    // ---- power iteration: each wave's copy initialized to 1/16 (wave-local)
    {
        v4t c = {0.0625f, 0.0625f, 0.0625f, 0.0625f};
        *(v4t*)(wme + wst) = c;
    }

    float y_last = 0.f, a_last = 1.f;
#pragma unroll 1
    for (int pi = 0; pi < NPOW; ++pi) {
        float y = matvec();
        stage[pi & 1][tid] = y;
        __syncthreads();
        v4t u4 = *(const v4t*)(&stage[pi & 1][4 * lane]);
        float ss = fmaf(u4.x, u4.x, fmaf(u4.y, u4.y, fmaf(u4.z, u4.z, u4.w * u4.w)));
        float a  = 1.f / (sqrtf(rdlane63(wave_sum63(ss))) + EPSF);
        v4t n4 = {a * u4.x, a * u4.y, a * u4.z, a * u4.w};
        *(v4t*)(wme + wst) = n4;          // full normalized vector, my copy
        y_last = y; a_last = a;
    }

    // ---- lmax = v' S v ; step
    float stepf;
    {
        float ysv = matvec();
        float p   = (a_last * y_last) * ysv;
        stage[0][tid] = p;
        __syncthreads();
        v4t p4 = *(const v4t*)(&stage[0][4 * lane]);
        float lmax = rdlane63(wave_sum63((p4.x + p4.y) + (p4.z + p4.w)));
        stepf = 1.f / (2.f * lmax + 2.f * lam2 + 1e-6f);
        __syncthreads();   // everyone done with stage[0] before PGD reuses it
    }

    // ---- PGD init: w0 = 1/256 (wave-local full copy)
    float w_own = 1.f / 256.f;
    {
        v4t c = {1.f/256.f, 1.f/256.f, 1.f/256.f, 1.f/256.f};
        *(v4t*)(wme + wst) = c;
    }
    const float Ac = 1.f - 2.f * lam2 * stepf;
    const float Bc = -2.f * stepf;
    const float Cc = stepf * (bt - lam1 + 2.f * lam2 * wp);

#pragma unroll 1
    for (int it = 0; it < NPGD; ++it) {
        float y = matvec();
        float v_own = fmaf(w_own, Ac, fmaf(y, Bc, Cc));
        const int sb = it & 1;
        stage[sb][tid] = v_own;
        __syncthreads();                      // the ONLY barrier this iteration

        v4t v4 = *(const v4t*)(&stage[sb][4 * lane]);
        float mn = rdlane63(wave_min63(fminf(fminf(v4.x, v4.y), fminf(v4.z, v4.w))));
        float mx = rdlane63(wave_max63(fmaxf(fmaxf(v4.x, v4.y), fmaxf(v4.z, v4.w))));

        // Illinois regula-falsi on f(tau)=s(tau)-1; known bracket values:
        //   s(mn-MAXW)=256*MAXW, s(mx)=0
        float lo = mn - MAXW, flo = 256.f * MAXW - 1.f;
        float hi = mx,        fhi = -1.f;
        int side = 0;
        float tau = 0.f;
#pragma unroll 1
        for (int r = 0; r < NILL; ++r) {
            tau = (lo * fhi - hi * flo) * __builtin_amdgcn_rcpf(fhi - flo);
            float c0 = __builtin_amdgcn_fmed3f(v4.x - tau, 0.f, MAXW);
            float c1 = __builtin_amdgcn_fmed3f(v4.y - tau, 0.f, MAXW);
            float c2 = __builtin_amdgcn_fmed3f(v4.z - tau, 0.f, MAXW);
            float c3 = __builtin_amdgcn_fmed3f(v4.w - tau, 0.f, MAXW);
            float f = rdlane63(wave_sum63((c0 + c1) + (c2 + c3))) - 1.f;
            bool pos = f > 0.f;
            float nflo = pos ? f   : ((side < 0) ? 0.5f * flo : flo);
            float nfhi = pos ? ((side > 0) ? 0.5f * fhi : fhi) : f;
            lo  = pos ? tau : lo;
            hi  = pos ? hi  : tau;
            flo = nflo; fhi = nfhi;
            side = pos ? 1 : -1;
        }
        tau = (lo * fhi - hi * flo) * __builtin_amdgcn_rcpf(fhi - flo);

        v4t w4 = {__builtin_amdgcn_fmed3f(v4.x - tau, 0.f, MAXW),
                  __builtin_amdgcn_fmed3f(v4.y - tau, 0.f, MAXW),
                  __builtin_amdgcn_fmed3f(v4.z - tau, 0.f, MAXW),
                  __builtin_amdgcn_fmed3f(v4.w - tau, 0.f, MAXW)};
        *(v4t*)(wme + wst) = w4;              // full projected w, my wave's copy
        w_own = __builtin_amdgcn_fmed3f(v_own - tau, 0.f, MAXW);
    }

    // ---- renormalize + store
    stage[0][tid] = w_own;
    __syncthreads();
    v4t w4 = *(const v4t*)(&stage[0][4 * lane]);
    float S = rdlane63(wave_sum63((w4.x + w4.y) + (w4.z + w4.w)));
    out[b * PP + tid] = w_own / (S + EPSF);
}

extern "C" void kernel_launch(void* const* d_in, const int* in_sizes, int n_in,
                              void* d_out, int out_size, void* d_ws, size_t ws_size,
                              hipStream_t stream) {
    const float* sigma  = (const float*)d_in[0];
    const float* beta   = (const float*)d_in[1];
    const float* wprevp = (const float*)d_in[2];
    const float* pl1    = (const float*)d_in[3];
    const float* pl2    = (const float*)d_in[4];
    float* outp = (float*)d_out;
    drb_kernel<<<dim3(512), dim3(256), 0, stream>>>(sigma, beta, wprevp, pl1, pl2, outp);
}

// Round 6
// 851.505 us; speedup vs baseline: 2.8294x; 1.0053x over previous
//
#include <hip/hip_runtime.h>
#include <math.h>

// DifferentiableRiskBudgeting: B=512, P=256. One block (256 thr) per batch.
// Thread (ti=tid>>2, tj=tid&3) owns rows 4ti..4ti+3 x cols 64tj..64tj+63.
//   Rows +0..2: fp32 VGPRs as <2 x float> pairs -> v_pk_fma_f32.
//   Row  +3: fp32 LDS slab, stride 272 + tj-stride 68 (conflict-free b128).
// R6: amdgpu_waves_per_eu(2,2) — LDS caps us at 2 blocks/CU anyway, so let
// the register allocator use the full 256 arch-VGPR budget. Without it the
// compiler targeted 4 waves/EU (128 regs) and spilled the 192-float sigma
// tile to AGPRs, paying v_accvgpr_read per FMA operand (~2.5x VALU inflation;
// VGPR_Count stuck at 128 in R3-R5 was the tell).
// One barrier per PGD iteration (wave-local w copies, double-buffered stage).
// Projection: 10-round Illinois regula-falsi, v_rcp_f32 secant.

#define PP    256
#define MAXW  0.1f
#define EPSF  1e-8f
#define NPGD  250
#define NPOW  20
#define NILL  10

#define R3S   272   // sigma row-3 slab stride (floats); 272 % 32 == 16
#define TJS   68    // tj stride inside slab row;        68 % 32 == 4
#define WRDS  72    // w-copy block stride (64 data + 8 stagger)
#define VCOPY 280   // per-wave w copy stride

typedef float v2 __attribute__((ext_vector_type(2)));
typedef float v4t __attribute__((ext_vector_type(4)));

template<int CTRL>
__device__ __forceinline__ float dpp_zero(float x) {
    return __int_as_float(__builtin_amdgcn_update_dpp(
        0, __float_as_int(x), CTRL, 0xF, 0xF, true));
}
template<int CTRL>
__device__ __forceinline__ float dpp_keep(float x) {
    int xi = __float_as_int(x);
    return __int_as_float(__builtin_amdgcn_update_dpp(xi, xi, CTRL, 0xF, 0xF, false));
}
__device__ __forceinline__ float rdlane63(float x) {
    return __int_as_float(__builtin_amdgcn_readlane(__float_as_int(x), 63));
}
__device__ __forceinline__ float wave_sum63(float s) {
    s += dpp_zero<0x111>(s);
    s += dpp_zero<0x112>(s);
    s += dpp_zero<0x114>(s);
    s += dpp_zero<0x118>(s);
    s += dpp_zero<0x142>(s);
    s += dpp_zero<0x143>(s);
    return s;
}
__device__ __forceinline__ float wave_min63(float m) {
    m = fminf(m, dpp_keep<0x111>(m));
    m = fminf(m, dpp_keep<0x112>(m));
    m = fminf(m, dpp_keep<0x114>(m));
    m = fminf(m, dpp_keep<0x118>(m));
    m = fminf(m, dpp_keep<0x142>(m));
    m = fminf(m, dpp_keep<0x143>(m));
    return m;
}
__device__ __forceinline__ float wave_max63(float m) {
    m = fmaxf(m, dpp_keep<0x111>(m));
    m = fmaxf(m, dpp_keep<0x112>(m));
    m = fmaxf(m, dpp_keep<0x114>(m));
    m = fmaxf(m, dpp_keep<0x118>(m));
    m = fmaxf(m, dpp_keep<0x142>(m));
    m = fmaxf(m, dpp_keep<0x143>(m));
    return m;
}

__global__ __launch_bounds__(256)
__attribute__((amdgpu_waves_per_eu(2, 2)))
void drb_kernel(const float* __restrict__ sigma,
                const float* __restrict__ beta,
                const float* __restrict__ wprev,
                const float* __restrict__ pl1,
                const float* __restrict__ pl2,
                float* __restrict__ out)
{
    const int b    = blockIdx.x;
    const int tid  = threadIdx.x;
    const int lane = tid & 63;
    const int wv   = tid >> 6;
    const int ti   = tid >> 2;   // 0..63
    const int tj   = tid & 3;    // 0..3

    __shared__ __align__(16) float sigR3[64 * R3S];   // 69632 B
    __shared__ __align__(16) float wcop[4 * VCOPY];   //  4480 B
    __shared__ __align__(16) float stage[2][256];     //  2048 B

    const float* Sb = sigma + (size_t)b * (PP * PP);

    // ---- stage sigma: rows +0..2 -> v2 VGPR pairs; row +3 -> LDS slab
    v2 s0[32], s1[32], s2[32];
    {
        const float* r0 = Sb + (4 * ti + 0) * PP + 64 * tj;
        const float* r1 = Sb + (4 * ti + 1) * PP + 64 * tj;
        const float* r2 = Sb + (4 * ti + 2) * PP + 64 * tj;
#pragma unroll
        for (int k = 0; k < 16; ++k) {
            v4t t0 = *(const v4t*)(r0 + 4 * k);
            v4t t1 = *(const v4t*)(r1 + 4 * k);
            v4t t2 = *(const v4t*)(r2 + 4 * k);
            s0[2*k]   = __builtin_shufflevector(t0, t0, 0, 1);
            s0[2*k+1] = __builtin_shufflevector(t0, t0, 2, 3);
            s1[2*k]   = __builtin_shufflevector(t1, t1, 0, 1);
            s1[2*k+1] = __builtin_shufflevector(t1, t1, 2, 3);
            s2[2*k]   = __builtin_shufflevector(t2, t2, 0, 1);
            s2[2*k+1] = __builtin_shufflevector(t2, t2, 2, 3);
        }
        const float* r3 = Sb + (4 * ti + 3) * PP + 64 * tj;
        float* d3 = sigR3 + ti * R3S + TJS * tj;
#pragma unroll
        for (int k = 0; k < 16; ++k)
            *(v4t*)(d3 + 4 * k) = *(const v4t*)(r3 + 4 * k);
        // row-3 slab is written and read by the SAME thread -> no barrier.
    }

    const float bt   = beta[b * PP + tid];
    const float wp   = wprev[b * PP + tid];
    const float lam1 = expf(pl1[0]);
    const float lam2 = expf(pl2[0]);

    float* wme = wcop + wv * VCOPY;                // my wave's full-vector copy
    const int wst = 4 * lane + 8 * (lane >> 4);    // staggered write slot
    const float* wrd = wme + WRDS * tj;            // matvec read base (72*tj)

    // y = Sigma * w (w from my wave's copy); returns y[row tid]
    auto matvec = [&]() -> float {
        v2 y0 = {0.f, 0.f}, y1 = {0.f, 0.f}, y2 = {0.f, 0.f}, y3 = {0.f, 0.f};
        const float* p3 = sigR3 + ti * R3S + TJS * tj;
#pragma unroll
        for (int k = 0; k < 16; ++k) {
            v4t wq = *(const v4t*)(wrd + 4 * k);
            v2 w01 = __builtin_shufflevector(wq, wq, 0, 1);
            v2 w23 = __builtin_shufflevector(wq, wq, 2, 3);
            y0 = __builtin_elementwise_fma(s0[2*k],   w01, y0);
            y0 = __builtin_elementwise_fma(s0[2*k+1], w23, y0);
            y1 = __builtin_elementwise_fma(s1[2*k],   w01, y1);
            y1 = __builtin_elementwise_fma(s1[2*k+1], w23, y1);
            y2 = __builtin_elementwise_fma(s2[2*k],   w01, y2);
            y2 = __builtin_elementwise_fma(s2[2*k+1], w23, y2);
            v4t q = *(const v4t*)(p3 + 4 * k);
            v2 q01 = __builtin_shufflevector(q, q, 0, 1);
            v2 q23 = __builtin_shufflevector(q, q, 2, 3);
            y3 = __builtin_elementwise_fma(q01, w01, y3);
            y3 = __builtin_elementwise_fma(q23, w23, y3);
        }
        float r0 = y0.x + y0.y, r1 = y1.x + y1.y;
        float r2 = y2.x + y2.y, r3 = y3.x + y3.y;
        r0 += dpp_zero<0x4E>(r0); r1 += dpp_zero<0x4E>(r1);
        r2 += dpp_zero<0x4E>(r2); r3 += dpp_zero<0x4E>(r3);
        r0 += dpp_zero<0xB1>(r0); r1 += dpp_zero<0xB1>(r1);
        r2 += dpp_zero<0xB1>(r2); r3 += dpp_zero<0xB1>(r3);
        float a01 = (tj & 1) ? r1 : r0;
        float a23 = (tj & 1) ? r3 : r2;
        return (tj & 2) ? a23 : a01;
    };

    // ---- power iteration: each wave's copy initialized to 1/16 (wave-local)
    {
        v4t c = {0.0625f, 0.0625f, 0.0625f, 0.0625f};
        *(v4t*)(wme + wst) = c;
    }

    float y_last = 0.f, a_last = 1.f;
#pragma unroll 1
    for (int pi = 0; pi < NPOW; ++pi) {
        float y = matvec();
        stage[pi & 1][tid] = y;
        __syncthreads();
        v4t u4 = *(const v4t*)(&stage[pi & 1][4 * lane]);
        float ss = fmaf(u4.x, u4.x, fmaf(u4.y, u4.y, fmaf(u4.z, u4.z, u4.w * u4.w)));
        float a  = 1.f / (sqrtf(rdlane63(wave_sum63(ss))) + EPSF);
        v4t n4 = {a * u4.x, a * u4.y, a * u4.z, a * u4.w};
        *(v4t*)(wme + wst) = n4;          // full normalized vector, my copy
        y_last = y; a_last = a;
    }

    // ---- lmax = v' S v ; step
    float stepf;
    {
        float ysv = matvec();
        float p   = (a_last * y_last) * ysv;
        stage[0][tid] = p;
        __syncthreads();
        v4t p4 = *(const v4t*)(&stage[0][4 * lane]);
        float lmax = rdlane63(wave_sum63((p4.x + p4.y) + (p4.z + p4.w)));
        stepf = 1.f / (2.f * lmax + 2.f * lam2 + 1e-6f);
        __syncthreads();   // everyone done with stage[0] before PGD reuses it
    }

    // ---- PGD init: w0 = 1/256 (wave-local full copy)
    float w_own = 1.f / 256.f;
    {
        v4t c = {1.f/256.f, 1.f/256.f, 1.f/256.f, 1.f/256.f};
        *(v4t*)(wme + wst) = c;
    }
    const float Ac = 1.f - 2.f * lam2 * stepf;
    const float Bc = -2.f * stepf;
    const float Cc = stepf * (bt - lam1 + 2.f * lam2 * wp);

#pragma unroll 1
    for (int it = 0; it < NPGD; ++it) {
        float y = matvec();
        float v_own = fmaf(w_own, Ac, fmaf(y, Bc, Cc));
        const int sb = it & 1;
        stage[sb][tid] = v_own;
        __syncthreads();                      // the ONLY barrier this iteration

        v4t v4 = *(const v4t*)(&stage[sb][4 * lane]);
        float mn = rdlane63(wave_min63(fminf(fminf(v4.x, v4.y), fminf(v4.z, v4.w))));
        float mx = rdlane63(wave_max63(fmaxf(fmaxf(v4.x, v4.y), fmaxf(v4.z, v4.w))));

        // Illinois regula-falsi on f(tau)=s(tau)-1; known bracket values:
        //   s(mn-MAXW)=256*MAXW, s(mx)=0
        float lo = mn - MAXW, flo = 256.f * MAXW - 1.f;
        float hi = mx,        fhi = -1.f;
        int side = 0;
        float tau = 0.f;
#pragma unroll 1
        for (int r = 0; r < NILL; ++r) {
            tau = (lo * fhi - hi * flo) * __builtin_amdgcn_rcpf(fhi - flo);
            float c0 = __builtin_amdgcn_fmed3f(v4.x - tau, 0.f, MAXW);
            float c1 = __builtin_amdgcn_fmed3f(v4.y - tau, 0.f, MAXW);
            float c2 = __builtin_amdgcn_fmed3f(v4.z - tau, 0.f, MAXW);
            float c3 = __builtin_amdgcn_fmed3f(v4.w - tau, 0.f, MAXW);
            float f = rdlane63(wave_sum63((c0 + c1) + (c2 + c3))) - 1.f;
            bool pos = f > 0.f;
            float nflo = pos ? f   : ((side < 0) ? 0.5f * flo : flo);
            float nfhi = pos ? ((side > 0) ? 0.5f * fhi : fhi) : f;
            lo  = pos ? tau : lo;
            hi  = pos ? hi  : tau;
            flo = nflo; fhi = nfhi;
            side = pos ? 1 : -1;
        }
        tau = (lo * fhi - hi * flo) * __builtin_amdgcn_rcpf(fhi - flo);

        v4t w4 = {__builtin_amdgcn_fmed3f(v4.x - tau, 0.f, MAXW),
                  __builtin_amdgcn_fmed3f(v4.y - tau, 0.f, MAXW),
                  __builtin_amdgcn_fmed3f(v4.z - tau, 0.f, MAXW),
                  __builtin_amdgcn_fmed3f(v4.w - tau, 0.f, MAXW)};
        *(v4t*)(wme + wst) = w4;              // full projected w, my wave's copy
        w_own = __builtin_amdgcn_fmed3f(v_own - tau, 0.f, MAXW);
    }

    // ---- renormalize + store
    stage[0][tid] = w_own;
    __syncthreads();
    v4t w4 = *(const v4t*)(&stage[0][4 * lane]);
    float S = rdlane63(wave_sum63((w4.x + w4.y) + (w4.z + w4.w)));
    out[b * PP + tid] = w_own / (S + EPSF);
}

extern "C" void kernel_launch(void* const* d_in, const int* in_sizes, int n_in,
                              void* d_out, int out_size, void* d_ws, size_t ws_size,
                              hipStream_t stream) {
    const float* sigma  = (const float*)d_in[0];
    const float* beta   = (const float*)d_in[1];
    const float* wprevp = (const float*)d_in[2];
    const float* pl1    = (const float*)d_in[3];
    const float* pl2    = (const float*)d_in[4];
    float* outp = (float*)d_out;
    drb_kernel<<<dim3(512), dim3(256), 0, stream>>>(sigma, beta, wprevp, pl1, pl2, outp);
}